// Round 1
// baseline (1581.469 us; speedup 1.0000x reference)
//
#include <hip/hip_runtime.h>
#include <hip/hip_bf16.h>
#include <math.h>

// Problem constants (fixed by the reference)
#define N_NODES   100000
#define N_EDGES   1000000
#define D_IN      64
#define T_ET      4
#define H_DIM     256
#define TD        256   // T_ET * D_IN (mlp fan-in)
#define G3        192   // 3 * D_IN (GRU gate width)

// ---------------------------------------------------------------------------
// Kernel 1: scatter  update[dst][type*64 + d] += w_e * x[src][d]
// 16 threads per edge, each handles a float4 (4 atomicAdds).
// ---------------------------------------------------------------------------
__global__ __launch_bounds__(256) void scatter_kernel(
    const float* __restrict__ x,          // [N, 64]
    const int*   __restrict__ edge_index, // [2, E]
    const int*   __restrict__ edge_type,  // [E]
    const float* __restrict__ edge_w,     // [E]
    float*       __restrict__ update)     // [N, 256]
{
    int tid = blockIdx.x * 256 + threadIdx.x;
    int e = tid >> 4;        // edge id
    int t = tid & 15;        // float4 slot within the 64-wide feature
    if (e >= N_EDGES) return;
    int   src = edge_index[e];
    int   dst = edge_index[N_EDGES + e];
    int   ty  = edge_type[e];
    float w   = edge_w[e];
    const float4 xv = reinterpret_cast<const float4*>(x)[src * 16 + t];
    float* base = update + (size_t)dst * TD + ty * D_IN + t * 4;
    atomicAdd(base + 0, w * xv.x);
    atomicAdd(base + 1, w * xv.y);
    atomicAdd(base + 2, w * xv.z);
    atomicAdd(base + 3, w * xv.w);
}

// ---------------------------------------------------------------------------
// Kernel 2: hidden = relu(update @ mlp_W^T + mlp_b)
// A: [M=100000, K=256]  B: [256, K=256] (row-major, K fast)  C: [M, 256]
// Tiled f32 GEMM, BM=BN=BK=64, 256 threads, 4x4 micro-tile per thread.
// LDS tiles stored transposed (k-major) so inner loop reads are float4.
// ---------------------------------------------------------------------------
__global__ __launch_bounds__(256) void gemm1_kernel(
    const float* __restrict__ A,     // update [N, 256]
    const float* __restrict__ B,     // mlp_W  [256, 256]
    const float* __restrict__ bias,  // mlp_b  [256]
    float*       __restrict__ C)     // hidden [N, 256]
{
    __shared__ float As[64][68];  // As[k][m]  (272B rows -> 16B aligned float4)
    __shared__ float Bs[64][68];  // Bs[k][n]

    const int tid = threadIdx.x;
    const int ty = tid >> 4;      // 0..15 -> 4 rows each
    const int tx = tid & 15;      // 0..15 -> 4 cols each
    const int rowBase = blockIdx.x * 64;
    const int colBase = blockIdx.y * 64;

    float acc[4][4] = {};

    for (int kt = 0; kt < 256; kt += 64) {
        __syncthreads();
        // stage A tile (guard rows)
        #pragma unroll
        for (int i = 0; i < 16; ++i) {
            int idx = i * 256 + tid;
            int k = idx & 63, r = idx >> 6;
            int row = rowBase + r;
            float v = 0.0f;
            if (row < N_NODES) v = A[(size_t)row * 256 + kt + k];
            As[k][r] = v;
        }
        // stage B tile (256 rows exact, no guard)
        #pragma unroll
        for (int i = 0; i < 16; ++i) {
            int idx = i * 256 + tid;
            int k = idx & 63, r = idx >> 6;
            Bs[k][r] = B[(size_t)(colBase + r) * 256 + kt + k];
        }
        __syncthreads();

        #pragma unroll
        for (int k = 0; k < 64; ++k) {
            const float4 a4 = *reinterpret_cast<const float4*>(&As[k][ty * 4]);
            const float4 b4 = *reinterpret_cast<const float4*>(&Bs[k][tx * 4]);
            const float a[4] = {a4.x, a4.y, a4.z, a4.w};
            const float b[4] = {b4.x, b4.y, b4.z, b4.w};
            #pragma unroll
            for (int i = 0; i < 4; ++i)
                #pragma unroll
                for (int j = 0; j < 4; ++j)
                    acc[i][j] += a[i] * b[j];
        }
    }

    const float4 bb = *reinterpret_cast<const float4*>(&bias[colBase + tx * 4]);
    const float bv[4] = {bb.x, bb.y, bb.z, bb.w};
    #pragma unroll
    for (int i = 0; i < 4; ++i) {
        int row = rowBase + ty * 4 + i;
        if (row < N_NODES) {
            float4 o;
            o.x = fmaxf(acc[i][0] + bv[0], 0.0f);
            o.y = fmaxf(acc[i][1] + bv[1], 0.0f);
            o.z = fmaxf(acc[i][2] + bv[2], 0.0f);
            o.w = fmaxf(acc[i][3] + bv[3], 0.0f);
            *reinterpret_cast<float4*>(&C[(size_t)row * 256 + colBase + tx * 4]) = o;
        }
    }
}

// ---------------------------------------------------------------------------
// Kernel 3: fused GRU
//   gi = hidden @ w_ih^T + b_ih   (K=256, 192 cols)
//   gh = x      @ w_hh^T + b_hh   (K=64, 192 cols)
//   r = sig(i_r+h_r); z = sig(i_z+h_z); n = tanh(i_n + r*h_n)
//   out = (1-z)*n + z*x
// 64-node tile per block; cols organized as 3 gate-chunks of 64 so each
// thread holds matched (r,z,n) triplets: thread (ty,tx) owns rows ty*4..+3
// and cols {tx*4..+3} of each gate chunk.
// ---------------------------------------------------------------------------
__global__ __launch_bounds__(256) void gru_kernel(
    const float* __restrict__ hidden, // [N, 256]
    const float* __restrict__ x,      // [N, 64]
    const float* __restrict__ w_ih,   // [192, 256]
    const float* __restrict__ w_hh,   // [192, 64]
    const float* __restrict__ b_ih,   // [192]
    const float* __restrict__ b_hh,   // [192]
    float*       __restrict__ out)    // [N, 64]
{
    __shared__ float As[32][68];      // As[k][row]
    __shared__ float Bs[3][32][68];   // Bs[gate][k][col]

    const int tid = threadIdx.x;
    const int ty = tid >> 4;
    const int tx = tid & 15;
    const int rowBase = blockIdx.x * 64;

    float acc_i[4][3][4] = {};
    float acc_h[4][3][4] = {};

    // ---- gi accumulation: K=256 in 8 tiles of 32 ----
    for (int kt = 0; kt < 256; kt += 32) {
        __syncthreads();
        // A tile: 64 rows x 32 k = 2048 elems / 256 thr = 8
        #pragma unroll
        for (int i = 0; i < 8; ++i) {
            int idx = i * 256 + tid;
            int k = idx & 31, r = idx >> 5;
            int row = rowBase + r;
            if (row >= N_NODES) row = N_NODES - 1;  // clamp, store is guarded
            As[k][r] = hidden[(size_t)row * 256 + kt + k];
        }
        // B tiles: 3 gates x 64 cols x 32 k = 6144 / 256 = 24
        #pragma unroll
        for (int i = 0; i < 24; ++i) {
            int idx = i * 256 + tid;
            int k = idx & 31;
            int rr = idx >> 5;          // 0..191
            int g = rr >> 6, j = rr & 63;
            Bs[g][k][j] = w_ih[(size_t)(g * 64 + j) * 256 + kt + k];
        }
        __syncthreads();

        #pragma unroll
        for (int k = 0; k < 32; ++k) {
            const float4 a4 = *reinterpret_cast<const float4*>(&As[k][ty * 4]);
            const float a[4] = {a4.x, a4.y, a4.z, a4.w};
            #pragma unroll
            for (int g = 0; g < 3; ++g) {
                const float4 b4 = *reinterpret_cast<const float4*>(&Bs[g][k][tx * 4]);
                const float b[4] = {b4.x, b4.y, b4.z, b4.w};
                #pragma unroll
                for (int i = 0; i < 4; ++i)
                    #pragma unroll
                    for (int j = 0; j < 4; ++j)
                        acc_i[i][g][j] += a[i] * b[j];
            }
        }
    }

    // ---- gh accumulation: K=64 in 2 tiles of 32 ----
    for (int kt = 0; kt < 64; kt += 32) {
        __syncthreads();
        #pragma unroll
        for (int i = 0; i < 8; ++i) {
            int idx = i * 256 + tid;
            int k = idx & 31, r = idx >> 5;
            int row = rowBase + r;
            if (row >= N_NODES) row = N_NODES - 1;
            As[k][r] = x[(size_t)row * 64 + kt + k];
        }
        #pragma unroll
        for (int i = 0; i < 24; ++i) {
            int idx = i * 256 + tid;
            int k = idx & 31;
            int rr = idx >> 5;
            int g = rr >> 6, j = rr & 63;
            Bs[g][k][j] = w_hh[(size_t)(g * 64 + j) * 64 + kt + k];
        }
        __syncthreads();

        #pragma unroll
        for (int k = 0; k < 32; ++k) {
            const float4 a4 = *reinterpret_cast<const float4*>(&As[k][ty * 4]);
            const float a[4] = {a4.x, a4.y, a4.z, a4.w};
            #pragma unroll
            for (int g = 0; g < 3; ++g) {
                const float4 b4 = *reinterpret_cast<const float4*>(&Bs[g][k][tx * 4]);
                const float b[4] = {b4.x, b4.y, b4.z, b4.w};
                #pragma unroll
                for (int i = 0; i < 4; ++i)
                    #pragma unroll
                    for (int j = 0; j < 4; ++j)
                        acc_h[i][g][j] += a[i] * b[j];
            }
        }
    }

    // ---- gates + output ----
    const int c0 = tx * 4;
    float bi[3][4], bh[3][4];
    #pragma unroll
    for (int g = 0; g < 3; ++g) {
        const float4 v1 = *reinterpret_cast<const float4*>(&b_ih[g * 64 + c0]);
        const float4 v2 = *reinterpret_cast<const float4*>(&b_hh[g * 64 + c0]);
        bi[g][0] = v1.x; bi[g][1] = v1.y; bi[g][2] = v1.z; bi[g][3] = v1.w;
        bh[g][0] = v2.x; bh[g][1] = v2.y; bh[g][2] = v2.z; bh[g][3] = v2.w;
    }

    #pragma unroll
    for (int i = 0; i < 4; ++i) {
        int row = rowBase + ty * 4 + i;
        if (row >= N_NODES) break;
        const float4 xv4 = *reinterpret_cast<const float4*>(&x[(size_t)row * 64 + c0]);
        const float xv[4] = {xv4.x, xv4.y, xv4.z, xv4.w};
        float o[4];
        #pragma unroll
        for (int j = 0; j < 4; ++j) {
            float ir = acc_i[i][0][j] + bi[0][j];
            float iz = acc_i[i][1][j] + bi[1][j];
            float in_ = acc_i[i][2][j] + bi[2][j];
            float hr = acc_h[i][0][j] + bh[0][j];
            float hz = acc_h[i][1][j] + bh[1][j];
            float hn = acc_h[i][2][j] + bh[2][j];
            float r = 1.0f / (1.0f + expf(-(ir + hr)));
            float z = 1.0f / (1.0f + expf(-(iz + hz)));
            float n = tanhf(in_ + r * hn);
            o[j] = (1.0f - z) * n + z * xv[j];
        }
        float4 o4 = {o[0], o[1], o[2], o[3]};
        *reinterpret_cast<float4*>(&out[(size_t)row * 64 + c0]) = o4;
    }
}

// ---------------------------------------------------------------------------
extern "C" void kernel_launch(void* const* d_in, const int* in_sizes, int n_in,
                              void* d_out, int out_size, void* d_ws, size_t ws_size,
                              hipStream_t stream) {
    const float* node_feature = (const float*)d_in[0];
    const int*   edge_index   = (const int*)d_in[1];
    const int*   edge_type    = (const int*)d_in[2];
    const float* edge_weight  = (const float*)d_in[3];
    const float* mlp_W        = (const float*)d_in[4];
    const float* mlp_b        = (const float*)d_in[5];
    const float* w_ih         = (const float*)d_in[6];
    const float* w_hh         = (const float*)d_in[7];
    const float* b_ih         = (const float*)d_in[8];
    const float* b_hh         = (const float*)d_in[9];
    float* out = (float*)d_out;

    float* update = (float*)d_ws;                        // [N, 256] f32
    float* hidden = (float*)d_ws + (size_t)N_NODES * TD; // [N, 256] f32

    // zero the scatter target (ws is poisoned 0xAA before every call)
    hipMemsetAsync(update, 0, (size_t)N_NODES * TD * sizeof(float), stream);

    // scatter: 16 threads/edge
    scatter_kernel<<<(N_EDGES * 16) / 256, 256, 0, stream>>>(
        node_feature, edge_index, edge_type, edge_weight, update);

    // hidden = relu(update @ mlp_W^T + mlp_b)
    gemm1_kernel<<<dim3((N_NODES + 63) / 64, H_DIM / 64), 256, 0, stream>>>(
        update, mlp_W, mlp_b, hidden);

    // fused GRU -> out
    gru_kernel<<<(N_NODES + 63) / 64, 256, 0, stream>>>(
        hidden, node_feature, w_ih, w_hh, b_ih, b_hh, out);
}

// Round 4
// 868.501 us; speedup vs baseline: 1.8209x; 1.8209x over previous
//
#include <hip/hip_runtime.h>
#include <hip/hip_bf16.h>
#include <math.h>

// Problem constants (fixed by the reference)
#define N_NODES   100000
#define N_EDGES   1000000
#define D_IN      64
#define T_ET      4
#define H_DIM     256
#define TD        256   // T_ET * D_IN (mlp fan-in)
#define NSEG      400000 // N_NODES * T_ET
#define G3        192   // 3 * D_IN (GRU gate width)

// ---------------------------------------------------------------------------
// CSR build: histogram -> scan -> place. Replaces 64M f32 atomics with 2M int
// atomics + a non-atomic gather.
// ---------------------------------------------------------------------------
__global__ __launch_bounds__(256) void hist_kernel(
    const int* __restrict__ edge_index, const int* __restrict__ edge_type,
    int* __restrict__ counts)
{
    int e = blockIdx.x * 256 + threadIdx.x;
    if (e >= N_EDGES) return;
    int dst = edge_index[N_EDGES + e];
    int ty  = edge_type[e];
    atomicAdd(&counts[dst * T_ET + ty], 1);
}

// scan level 1: 1024 elements / block (256 thr x 4), exclusive within block
__global__ __launch_bounds__(256) void scan1_kernel(
    const int* __restrict__ counts, int* __restrict__ offsets,
    int* __restrict__ partials)
{
    __shared__ int tsum[256];
    const int tid = threadIdx.x;
    const int base = blockIdx.x * 1024 + tid * 4;
    int v[4]; int s = 0;
    #pragma unroll
    for (int i = 0; i < 4; ++i) {
        v[i] = (base + i < NSEG) ? counts[base + i] : 0;
        s += v[i];
    }
    tsum[tid] = s;
    __syncthreads();
    #pragma unroll
    for (int off = 1; off < 256; off <<= 1) {
        int t = (tid >= off) ? tsum[tid - off] : 0;
        __syncthreads();
        tsum[tid] += t;
        __syncthreads();
    }
    int run = tsum[tid] - s;  // exclusive prefix of this thread within block
    #pragma unroll
    for (int i = 0; i < 4; ++i) {
        if (base + i < NSEG) offsets[base + i] = run;
        run += v[i];
    }
    if (tid == 255) partials[blockIdx.x] = tsum[255];
}

// scan level 2: single block of 512 scans the 391 block totals (exclusive)
__global__ __launch_bounds__(512) void scan2_kernel(int* __restrict__ partials, int nb)
{
    __shared__ int sh[512];
    const int tid = threadIdx.x;
    int v = (tid < nb) ? partials[tid] : 0;
    sh[tid] = v;
    __syncthreads();
    #pragma unroll
    for (int off = 1; off < 512; off <<= 1) {
        int t = (tid >= off) ? sh[tid - off] : 0;
        __syncthreads();
        sh[tid] += t;
        __syncthreads();
    }
    if (tid < nb) partials[tid] = sh[tid] - v;
}

// scan level 3: add block bases; duplicate into cursor; write offsets[NSEG]=E
__global__ __launch_bounds__(256) void scan3_kernel(
    int* __restrict__ offsets, const int* __restrict__ partials,
    int* __restrict__ cursor)
{
    int i = blockIdx.x * 256 + threadIdx.x;
    if (i < NSEG) {
        int o = offsets[i] + partials[i >> 10];
        offsets[i] = o;
        cursor[i]  = o;
    }
    if (i == 0) offsets[NSEG] = N_EDGES;
}

__global__ __launch_bounds__(256) void place_kernel(
    const int* __restrict__ edge_index, const int* __restrict__ edge_type,
    const float* __restrict__ edge_w, int* __restrict__ cursor,
    int2* __restrict__ recs)
{
    int e = blockIdx.x * 256 + threadIdx.x;
    if (e >= N_EDGES) return;
    int src = edge_index[e];
    int dst = edge_index[N_EDGES + e];
    int ty  = edge_type[e];
    int seg = dst * T_ET + ty;
    int pos = atomicAdd(&cursor[seg], 1);
    recs[pos] = make_int2(src, __float_as_int(edge_w[e]));
}

// gather: 16 threads per segment; each thread owns one float4 of the 64-wide
// feature. update[seg*64 + d] = sum over edges of w * x[src][d]. Non-atomic,
// writes every element (so no memset of update needed).
__global__ __launch_bounds__(256) void gather_kernel(
    const float* __restrict__ x, const int* __restrict__ offsets,
    const int2* __restrict__ recs, float* __restrict__ update)
{
    int gid = blockIdx.x * 256 + threadIdx.x;
    int seg = gid >> 4;
    int t   = gid & 15;
    if (seg >= NSEG) return;
    int start = offsets[seg];
    int end   = offsets[seg + 1];
    float4 acc = {0.0f, 0.0f, 0.0f, 0.0f};
    for (int p = start; p < end; ++p) {
        int2 r = recs[p];                 // broadcast across the 16 threads
        float w = __int_as_float(r.y);
        const float4 xv = reinterpret_cast<const float4*>(x)[r.x * 16 + t];
        acc.x += w * xv.x;
        acc.y += w * xv.y;
        acc.z += w * xv.z;
        acc.w += w * xv.w;
    }
    reinterpret_cast<float4*>(update)[seg * 16 + t] = acc;
}

// ---------------------------------------------------------------------------
// Kernel 2: hidden = relu(update @ mlp_W^T + mlp_b)
// Tiled f32 GEMM, BM=BN=BK=64, 256 threads, 4x4 micro-tile per thread.
// ---------------------------------------------------------------------------
__global__ __launch_bounds__(256) void gemm1_kernel(
    const float* __restrict__ A,     // update [N, 256]
    const float* __restrict__ B,     // mlp_W  [256, 256]
    const float* __restrict__ bias,  // mlp_b  [256]
    float*       __restrict__ C)     // hidden [N, 256]
{
    __shared__ float As[64][68];  // As[k][m]
    __shared__ float Bs[64][68];  // Bs[k][n]

    const int tid = threadIdx.x;
    const int ty = tid >> 4;
    const int tx = tid & 15;
    const int rowBase = blockIdx.x * 64;
    const int colBase = blockIdx.y * 64;

    float acc[4][4] = {};

    for (int kt = 0; kt < 256; kt += 64) {
        __syncthreads();
        #pragma unroll
        for (int i = 0; i < 16; ++i) {
            int idx = i * 256 + tid;
            int k = idx & 63, r = idx >> 6;
            int row = rowBase + r;
            float v = 0.0f;
            if (row < N_NODES) v = A[(size_t)row * 256 + kt + k];
            As[k][r] = v;
        }
        #pragma unroll
        for (int i = 0; i < 16; ++i) {
            int idx = i * 256 + tid;
            int k = idx & 63, r = idx >> 6;
            Bs[k][r] = B[(size_t)(colBase + r) * 256 + kt + k];
        }
        __syncthreads();

        #pragma unroll
        for (int k = 0; k < 64; ++k) {
            const float4 a4 = *reinterpret_cast<const float4*>(&As[k][ty * 4]);
            const float4 b4 = *reinterpret_cast<const float4*>(&Bs[k][tx * 4]);
            const float a[4] = {a4.x, a4.y, a4.z, a4.w};
            const float b[4] = {b4.x, b4.y, b4.z, b4.w};
            #pragma unroll
            for (int i = 0; i < 4; ++i)
                #pragma unroll
                for (int j = 0; j < 4; ++j)
                    acc[i][j] += a[i] * b[j];
        }
    }

    const float4 bb = *reinterpret_cast<const float4*>(&bias[colBase + tx * 4]);
    const float bv[4] = {bb.x, bb.y, bb.z, bb.w};
    #pragma unroll
    for (int i = 0; i < 4; ++i) {
        int row = rowBase + ty * 4 + i;
        if (row < N_NODES) {
            float4 o;
            o.x = fmaxf(acc[i][0] + bv[0], 0.0f);
            o.y = fmaxf(acc[i][1] + bv[1], 0.0f);
            o.z = fmaxf(acc[i][2] + bv[2], 0.0f);
            o.w = fmaxf(acc[i][3] + bv[3], 0.0f);
            *reinterpret_cast<float4*>(&C[(size_t)row * 256 + colBase + tx * 4]) = o;
        }
    }
}

// ---------------------------------------------------------------------------
// Kernel 3: fused GRU
// ---------------------------------------------------------------------------
__global__ __launch_bounds__(256) void gru_kernel(
    const float* __restrict__ hidden, // [N, 256]
    const float* __restrict__ x,      // [N, 64]
    const float* __restrict__ w_ih,   // [192, 256]
    const float* __restrict__ w_hh,   // [192, 64]
    const float* __restrict__ b_ih,   // [192]
    const float* __restrict__ b_hh,   // [192]
    float*       __restrict__ out)    // [N, 64]
{
    __shared__ float As[32][68];
    __shared__ float Bs[3][32][68];

    const int tid = threadIdx.x;
    const int ty = tid >> 4;
    const int tx = tid & 15;
    const int rowBase = blockIdx.x * 64;

    float acc_i[4][3][4] = {};
    float acc_h[4][3][4] = {};

    for (int kt = 0; kt < 256; kt += 32) {
        __syncthreads();
        #pragma unroll
        for (int i = 0; i < 8; ++i) {
            int idx = i * 256 + tid;
            int k = idx & 31, r = idx >> 5;
            int row = rowBase + r;
            if (row >= N_NODES) row = N_NODES - 1;
            As[k][r] = hidden[(size_t)row * 256 + kt + k];
        }
        #pragma unroll
        for (int i = 0; i < 24; ++i) {
            int idx = i * 256 + tid;
            int k = idx & 31;
            int rr = idx >> 5;
            int g = rr >> 6, j = rr & 63;
            Bs[g][k][j] = w_ih[(size_t)(g * 64 + j) * 256 + kt + k];
        }
        __syncthreads();

        #pragma unroll
        for (int k = 0; k < 32; ++k) {
            const float4 a4 = *reinterpret_cast<const float4*>(&As[k][ty * 4]);
            const float a[4] = {a4.x, a4.y, a4.z, a4.w};
            #pragma unroll
            for (int g = 0; g < 3; ++g) {
                const float4 b4 = *reinterpret_cast<const float4*>(&Bs[g][k][tx * 4]);
                const float b[4] = {b4.x, b4.y, b4.z, b4.w};
                #pragma unroll
                for (int i = 0; i < 4; ++i)
                    #pragma unroll
                    for (int j = 0; j < 4; ++j)
                        acc_i[i][g][j] += a[i] * b[j];
            }
        }
    }

    for (int kt = 0; kt < 64; kt += 32) {
        __syncthreads();
        #pragma unroll
        for (int i = 0; i < 8; ++i) {
            int idx = i * 256 + tid;
            int k = idx & 31, r = idx >> 5;
            int row = rowBase + r;
            if (row >= N_NODES) row = N_NODES - 1;
            As[k][r] = x[(size_t)row * 64 + kt + k];
        }
        #pragma unroll
        for (int i = 0; i < 24; ++i) {
            int idx = i * 256 + tid;
            int k = idx & 31;
            int rr = idx >> 5;
            int g = rr >> 6, j = rr & 63;
            Bs[g][k][j] = w_hh[(size_t)(g * 64 + j) * 64 + kt + k];
        }
        __syncthreads();

        #pragma unroll
        for (int k = 0; k < 32; ++k) {
            const float4 a4 = *reinterpret_cast<const float4*>(&As[k][ty * 4]);
            const float a[4] = {a4.x, a4.y, a4.z, a4.w};
            #pragma unroll
            for (int g = 0; g < 3; ++g) {
                const float4 b4 = *reinterpret_cast<const float4*>(&Bs[g][k][tx * 4]);
                const float b[4] = {b4.x, b4.y, b4.z, b4.w};
                #pragma unroll
                for (int i = 0; i < 4; ++i)
                    #pragma unroll
                    for (int j = 0; j < 4; ++j)
                        acc_h[i][g][j] += a[i] * b[j];
            }
        }
    }

    const int c0 = tx * 4;
    float bi[3][4], bh[3][4];
    #pragma unroll
    for (int g = 0; g < 3; ++g) {
        const float4 v1 = *reinterpret_cast<const float4*>(&b_ih[g * 64 + c0]);
        const float4 v2 = *reinterpret_cast<const float4*>(&b_hh[g * 64 + c0]);
        bi[g][0] = v1.x; bi[g][1] = v1.y; bi[g][2] = v1.z; bi[g][3] = v1.w;
        bh[g][0] = v2.x; bh[g][1] = v2.y; bh[g][2] = v2.z; bh[g][3] = v2.w;
    }

    #pragma unroll
    for (int i = 0; i < 4; ++i) {
        int row = rowBase + ty * 4 + i;
        if (row >= N_NODES) break;
        const float4 xv4 = *reinterpret_cast<const float4*>(&x[(size_t)row * 64 + c0]);
        const float xv[4] = {xv4.x, xv4.y, xv4.z, xv4.w};
        float o[4];
        #pragma unroll
        for (int j = 0; j < 4; ++j) {
            float ir = acc_i[i][0][j] + bi[0][j];
            float iz = acc_i[i][1][j] + bi[1][j];
            float in_ = acc_i[i][2][j] + bi[2][j];
            float hr = acc_h[i][0][j] + bh[0][j];
            float hz = acc_h[i][1][j] + bh[1][j];
            float hn = acc_h[i][2][j] + bh[2][j];
            float r = 1.0f / (1.0f + expf(-(ir + hr)));
            float z = 1.0f / (1.0f + expf(-(iz + hz)));
            float n = tanhf(in_ + r * hn);
            o[j] = (1.0f - z) * n + z * xv[j];
        }
        float4 o4 = {o[0], o[1], o[2], o[3]};
        *reinterpret_cast<float4*>(&out[(size_t)row * 64 + c0]) = o4;
    }
}

// ---------------------------------------------------------------------------
extern "C" void kernel_launch(void* const* d_in, const int* in_sizes, int n_in,
                              void* d_out, int out_size, void* d_ws, size_t ws_size,
                              hipStream_t stream) {
    const float* node_feature = (const float*)d_in[0];
    const int*   edge_index   = (const int*)d_in[1];
    const int*   edge_type    = (const int*)d_in[2];
    const float* edge_weight  = (const float*)d_in[3];
    const float* mlp_W        = (const float*)d_in[4];
    const float* mlp_b        = (const float*)d_in[5];
    const float* w_ih         = (const float*)d_in[6];
    const float* w_hh         = (const float*)d_in[7];
    const float* b_ih         = (const float*)d_in[8];
    const float* b_hh         = (const float*)d_in[9];
    float* out = (float*)d_out;

    float* update = (float*)d_ws;                        // [N, 256] f32
    float* hidden = (float*)d_ws + (size_t)N_NODES * TD; // [N, 256] f32

    // CSR aux buffers ALIAS the hidden region: they are dead before gemm1
    // writes hidden. (hist/scan/place/gather all complete first in-stream.)
    int* counts   = (int*)hidden;            // [NSEG]
    int* offsets  = counts + 400064;         // [NSEG+1]
    int* partials = offsets + 400064;        // [512]
    int* cursor   = partials + 512;          // [NSEG]
    int2* recs    = (int2*)(cursor + 400064);// [E] {src, w-bits} (8B aligned)

    const int NB1 = (NSEG + 1023) / 1024;    // 391 scan blocks

    hipMemsetAsync(counts, 0, (size_t)NSEG * sizeof(int), stream);

    hist_kernel<<<(N_EDGES + 255) / 256, 256, 0, stream>>>(
        edge_index, edge_type, counts);
    scan1_kernel<<<NB1, 256, 0, stream>>>(counts, offsets, partials);
    scan2_kernel<<<1, 512, 0, stream>>>(partials, NB1);
    scan3_kernel<<<(NSEG + 255) / 256, 256, 0, stream>>>(offsets, partials, cursor);
    place_kernel<<<(N_EDGES + 255) / 256, 256, 0, stream>>>(
        edge_index, edge_type, edge_weight, cursor, recs);
    gather_kernel<<<(NSEG * 16 + 255) / 256, 256, 0, stream>>>(
        node_feature, offsets, recs, update);

    gemm1_kernel<<<dim3((N_NODES + 63) / 64, H_DIM / 64), 256, 0, stream>>>(
        update, mlp_W, mlp_b, hidden);

    gru_kernel<<<(N_NODES + 63) / 64, 256, 0, stream>>>(
        hidden, node_feature, w_ih, w_hh, b_ih, b_hh, out);
}

// Round 5
// 489.701 us; speedup vs baseline: 3.2295x; 1.7735x over previous
//
#include <hip/hip_runtime.h>
#include <hip/hip_bf16.h>
#include <math.h>

// Problem constants (fixed by the reference)
#define N_NODES   100000
#define N_PAD     100032   // padded row count (multiple of 64) for safe OOB reads
#define N_EDGES   1000000
#define D_IN      64
#define T_ET      4
#define H_DIM     256
#define TD        256      // T_ET * D_IN (mlp fan-in)
#define NSEG      400000   // N_NODES * T_ET

typedef __attribute__((ext_vector_type(8))) short short8;   // 8 bf16 (4 VGPRs)
typedef __attribute__((ext_vector_type(4))) float floatx4;  // MFMA C/D

__device__ __forceinline__ unsigned short f2b(float f) {
    __hip_bfloat16 h = __float2bfloat16(f);
    return *reinterpret_cast<unsigned short*>(&h);
}
__device__ __forceinline__ unsigned pack2(float a, float b) {
    return (unsigned)f2b(a) | ((unsigned)f2b(b) << 16);
}

// ---------------------------------------------------------------------------
// CSR build (unchanged from round 4): histogram -> scan -> place
// ---------------------------------------------------------------------------
__global__ __launch_bounds__(256) void hist_kernel(
    const int* __restrict__ edge_index, const int* __restrict__ edge_type,
    int* __restrict__ counts)
{
    int e = blockIdx.x * 256 + threadIdx.x;
    if (e >= N_EDGES) return;
    int dst = edge_index[N_EDGES + e];
    int ty  = edge_type[e];
    atomicAdd(&counts[dst * T_ET + ty], 1);
}

__global__ __launch_bounds__(256) void scan1_kernel(
    const int* __restrict__ counts, int* __restrict__ offsets,
    int* __restrict__ partials)
{
    __shared__ int tsum[256];
    const int tid = threadIdx.x;
    const int base = blockIdx.x * 1024 + tid * 4;
    int v[4]; int s = 0;
    #pragma unroll
    for (int i = 0; i < 4; ++i) {
        v[i] = (base + i < NSEG) ? counts[base + i] : 0;
        s += v[i];
    }
    tsum[tid] = s;
    __syncthreads();
    #pragma unroll
    for (int off = 1; off < 256; off <<= 1) {
        int t = (tid >= off) ? tsum[tid - off] : 0;
        __syncthreads();
        tsum[tid] += t;
        __syncthreads();
    }
    int run = tsum[tid] - s;
    #pragma unroll
    for (int i = 0; i < 4; ++i) {
        if (base + i < NSEG) offsets[base + i] = run;
        run += v[i];
    }
    if (tid == 255) partials[blockIdx.x] = tsum[255];
}

__global__ __launch_bounds__(512) void scan2_kernel(int* __restrict__ partials, int nb)
{
    __shared__ int sh[512];
    const int tid = threadIdx.x;
    int v = (tid < nb) ? partials[tid] : 0;
    sh[tid] = v;
    __syncthreads();
    #pragma unroll
    for (int off = 1; off < 512; off <<= 1) {
        int t = (tid >= off) ? sh[tid - off] : 0;
        __syncthreads();
        sh[tid] += t;
        __syncthreads();
    }
    if (tid < nb) partials[tid] = sh[tid] - v;
}

__global__ __launch_bounds__(256) void scan3_kernel(
    int* __restrict__ offsets, const int* __restrict__ partials,
    int* __restrict__ cursor)
{
    int i = blockIdx.x * 256 + threadIdx.x;
    if (i < NSEG) {
        int o = offsets[i] + partials[i >> 10];
        offsets[i] = o;
        cursor[i]  = o;
    }
    if (i == 0) offsets[NSEG] = N_EDGES;
}

__global__ __launch_bounds__(256) void place_kernel(
    const int* __restrict__ edge_index, const int* __restrict__ edge_type,
    const float* __restrict__ edge_w, int* __restrict__ cursor,
    int2* __restrict__ recs)
{
    int e = blockIdx.x * 256 + threadIdx.x;
    if (e >= N_EDGES) return;
    int src = edge_index[e];
    int dst = edge_index[N_EDGES + e];
    int ty  = edge_type[e];
    int seg = dst * T_ET + ty;
    int pos = atomicAdd(&cursor[seg], 1);
    recs[pos] = make_int2(src, __float_as_int(edge_w[e]));
}

// gather: 16 threads per segment -> bf16 update (8B per thread per segment)
__global__ __launch_bounds__(256) void gather_kernel(
    const float* __restrict__ x, const int* __restrict__ offsets,
    const int2* __restrict__ recs, unsigned* __restrict__ updb_u32)
{
    int gid = blockIdx.x * 256 + threadIdx.x;
    int seg = gid >> 4;
    int t   = gid & 15;
    if (seg >= NSEG) return;
    int start = offsets[seg];
    int end   = offsets[seg + 1];
    float4 acc = {0.0f, 0.0f, 0.0f, 0.0f};
    for (int p = start; p < end; ++p) {
        int2 r = recs[p];
        float w = __int_as_float(r.y);
        const float4 xv = reinterpret_cast<const float4*>(x)[r.x * 16 + t];
        acc.x += w * xv.x;
        acc.y += w * xv.y;
        acc.z += w * xv.z;
        acc.w += w * xv.w;
    }
    uint2 o;
    o.x = pack2(acc.x, acc.y);
    o.y = pack2(acc.z, acc.w);
    reinterpret_cast<uint2*>(updb_u32)[seg * 16 + t] = o;  // update[seg][t*4..+4] bf16
}

// ---------------------------------------------------------------------------
// prep: f32 -> bf16 conversions (x padded; w_ih K-permuted to match the
// hidden-LDS pack layout: k(p) = 16*(p>>6) + 64*(p&3) + ((p>>2)&15))
// ---------------------------------------------------------------------------
__global__ __launch_bounds__(256) void conv_x_kernel(
    const float* __restrict__ x, unsigned short* __restrict__ xb)
{
    int i = blockIdx.x * 256 + threadIdx.x;          // one float4 per thread
    if (i >= N_PAD * 16) return;
    int row = i >> 4;
    int srow = row < N_NODES ? row : N_NODES - 1;
    float4 v = reinterpret_cast<const float4*>(x)[srow * 16 + (i & 15)];
    uint2 o;
    o.x = pack2(v.x, v.y);
    o.y = pack2(v.z, v.w);
    reinterpret_cast<uint2*>(xb)[i] = o;
}

__global__ __launch_bounds__(256) void conv_w_kernel(
    const float* __restrict__ w1, const float* __restrict__ wih,
    const float* __restrict__ whh,
    unsigned short* __restrict__ w1b, unsigned short* __restrict__ wihp,
    unsigned short* __restrict__ whhb)
{
    int i = blockIdx.x * 256 + threadIdx.x;
    if (i < 65536) { w1b[i] = f2b(w1[i]); return; }
    i -= 65536;
    if (i < 49152) {
        int n = i >> 8, p = i & 255;
        int k = 16 * (p >> 6) + 64 * (p & 3) + ((p >> 2) & 15);
        wihp[i] = f2b(wih[n * 256 + k]);
        return;
    }
    i -= 49152;
    if (i < 12288) whhb[i] = f2b(whh[i]);
}

// ---------------------------------------------------------------------------
// Fused MLP + GRU, bf16 MFMA (16x16x32), 64 rows/block, 4 waves, M-split:
// wave w owns rows blockIdx*64 + 16w .. +15. No __syncthreads (per-wave LDS).
// Phase 1: hidden = relu(upd @ W1^T + b1)   [16x256, K=256] -> per-wave LDS
// Phase 2: gi = hidden @ w_ih^T (K=256, permuted), gh = x @ w_hh^T (K=64)
// Gates thread-local (C-layout puts matched r/z/n cols in the same lane).
// ---------------------------------------------------------------------------
__global__ __launch_bounds__(256) void fused_mlp_gru_kernel(
    const unsigned short* __restrict__ updb,  // [N_PAD][256] bf16
    const unsigned short* __restrict__ w1b,   // [256][256] bf16
    const float* __restrict__ mlp_b,          // [256]
    const unsigned short* __restrict__ wihp,  // [192][256] bf16, K-permuted
    const unsigned short* __restrict__ whhb,  // [192][64]  bf16
    const float* __restrict__ b_ih,           // [192]
    const float* __restrict__ b_hh,           // [192]
    const float* __restrict__ x,              // [N][64] f32
    const unsigned short* __restrict__ xb,    // [N_PAD][64] bf16
    float* __restrict__ out)                  // [N][64] f32
{
    __shared__ unsigned short hid[4][16 * 256];  // 8 KB per wave, 32 KB total

    const int tid = threadIdx.x;
    const int w  = tid >> 6;
    const int l  = tid & 63;
    const int lr = l & 15;     // fragment M/N index
    const int lg = l >> 4;     // k-group (0..3)
    const int rowBase = blockIdx.x * 64 + w * 16;

    // ---- phase 1: acc1[nf] = rows(16) x cols(nf*16+lr), K=256 ----
    floatx4 acc1[16];
    #pragma unroll
    for (int i = 0; i < 16; ++i) acc1[i] = (floatx4){0.f, 0.f, 0.f, 0.f};

    const unsigned short* aRow = updb + (size_t)(rowBase + lr) * 256 + lg * 8;
    #pragma unroll
    for (int kt = 0; kt < 8; ++kt) {
        short8 af = *reinterpret_cast<const short8*>(aRow + kt * 32);
        #pragma unroll
        for (int nf = 0; nf < 16; ++nf) {
            short8 bf = *reinterpret_cast<const short8*>(
                w1b + (size_t)(nf * 16 + lr) * 256 + kt * 32 + lg * 8);
            acc1[nf] = __builtin_amdgcn_mfma_f32_16x16x32_bf16(af, bf, acc1[nf], 0, 0, 0);
        }
    }

    // bias per col (col = nf*16 + lr)
    float b1v[16];
    #pragma unroll
    for (int nf = 0; nf < 16; ++nf) b1v[nf] = mlp_b[nf * 16 + lr];

    // relu + pack to per-wave LDS. C layout: row=(lg*4+q), col=nf*16+lr.
    // Pack s=0..3 -> nf=jj+4s at bf16 position p = 64*jj + 4*lr + s
    // (=> k(p) = 16*jj + 64*s + lr, matched by wihp's prep permutation).
    // XOR swizzle ((row&7)<<4) breaks the 512B-row bank alignment.
    char* hw = reinterpret_cast<char*>(&hid[w][0]);
    #pragma unroll
    for (int jj = 0; jj < 4; ++jj) {
        #pragma unroll
        for (int q = 0; q < 4; ++q) {
            int row = lg * 4 + q;
            float v0 = fmaxf(acc1[jj     ][q] + b1v[jj     ], 0.f);
            float v1 = fmaxf(acc1[jj +  4][q] + b1v[jj +  4], 0.f);
            float v2 = fmaxf(acc1[jj +  8][q] + b1v[jj +  8], 0.f);
            float v3 = fmaxf(acc1[jj + 12][q] + b1v[jj + 12], 0.f);
            uint2 pk;
            pk.x = pack2(v0, v1);
            pk.y = pack2(v2, v3);
            int byte = (row * 512 + 128 * jj + 8 * lr) ^ ((row & 7) << 4);
            *reinterpret_cast<uint2*>(hw + byte) = pk;
        }
    }

    // ---- phase 2: gi (K=256 over permuted p) + gh (K=64) ----
    floatx4 ai[12], ah[12];
    #pragma unroll
    for (int i = 0; i < 12; ++i) { ai[i] = (floatx4){0.f,0.f,0.f,0.f}; ah[i] = (floatx4){0.f,0.f,0.f,0.f}; }

    #pragma unroll
    for (int kt = 0; kt < 8; ++kt) {
        int byte = (lr * 512 + kt * 64 + lg * 16) ^ ((lr & 7) << 4);
        short8 af = *reinterpret_cast<const short8*>(hw + byte);
        #pragma unroll
        for (int nf = 0; nf < 12; ++nf) {
            short8 bf = *reinterpret_cast<const short8*>(
                wihp + (size_t)(nf * 16 + lr) * 256 + kt * 32 + lg * 8);
            ai[nf] = __builtin_amdgcn_mfma_f32_16x16x32_bf16(af, bf, ai[nf], 0, 0, 0);
        }
    }

    const unsigned short* xRow = xb + (size_t)(rowBase + lr) * 64 + lg * 8;
    #pragma unroll
    for (int kt = 0; kt < 2; ++kt) {
        short8 af = *reinterpret_cast<const short8*>(xRow + kt * 32);
        #pragma unroll
        for (int nf = 0; nf < 12; ++nf) {
            short8 bf = *reinterpret_cast<const short8*>(
                whhb + (nf * 16 + lr) * 64 + kt * 32 + lg * 8);
            ah[nf] = __builtin_amdgcn_mfma_f32_16x16x32_bf16(af, bf, ah[nf], 0, 0, 0);
        }
    }

    // ---- gates + output (thread-local: r/z/n cols share the lane) ----
    #pragma unroll
    for (int nf = 0; nf < 4; ++nf) {
        int c = nf * 16 + lr;
        float bir = b_ih[c], biz = b_ih[64 + c], bin = b_ih[128 + c];
        float bhr = b_hh[c], bhz = b_hh[64 + c], bhn = b_hh[128 + c];
        #pragma unroll
        for (int q = 0; q < 4; ++q) {
            int row = rowBase + lg * 4 + q;
            if (row < N_NODES) {
                float ir = ai[nf    ][q] + bir;
                float iz = ai[nf + 4][q] + biz;
                float in_= ai[nf + 8][q] + bin;
                float hr = ah[nf    ][q] + bhr;
                float hz = ah[nf + 4][q] + bhz;
                float hn = ah[nf + 8][q] + bhn;
                float r = 1.0f / (1.0f + expf(-(ir + hr)));
                float z = 1.0f / (1.0f + expf(-(iz + hz)));
                float n = tanhf(in_ + r * hn);
                float xv = x[(size_t)row * 64 + c];
                out[(size_t)row * 64 + c] = (1.0f - z) * n + z * xv;
            }
        }
    }
}

// ---------------------------------------------------------------------------
extern "C" void kernel_launch(void* const* d_in, const int* in_sizes, int n_in,
                              void* d_out, int out_size, void* d_ws, size_t ws_size,
                              hipStream_t stream) {
    const float* node_feature = (const float*)d_in[0];
    const int*   edge_index   = (const int*)d_in[1];
    const int*   edge_type    = (const int*)d_in[2];
    const float* edge_weight  = (const float*)d_in[3];
    const float* mlp_W        = (const float*)d_in[4];
    const float* mlp_b        = (const float*)d_in[5];
    const float* w_ih         = (const float*)d_in[6];
    const float* w_hh         = (const float*)d_in[7];
    const float* b_ih         = (const float*)d_in[8];
    const float* b_hh         = (const float*)d_in[9];
    float* out = (float*)d_out;

    // workspace layout (bf16 regions first, then CSR ints) — ~90 MB total
    unsigned short* updb = (unsigned short*)d_ws;          // [N_PAD][256]
    unsigned short* xb   = updb + (size_t)N_PAD * 256;     // [N_PAD][64]
    unsigned short* w1b  = xb   + (size_t)N_PAD * 64;      // [256][256]
    unsigned short* wihp = w1b  + 65536;                   // [192][256]
    unsigned short* whhb = wihp + 49152;                   // [192][64]
    int* counts   = (int*)(whhb + 12288);                  // [NSEG]
    int* offsets  = counts + 400064;                       // [NSEG+1]
    int* partials = offsets + 400064;                      // [512]
    int* cursor   = partials + 512;                        // [NSEG]
    int2* recs    = (int2*)(cursor + 400064);              // [E]

    const int NB1 = (NSEG + 1023) / 1024;

    hipMemsetAsync(counts, 0, (size_t)NSEG * sizeof(int), stream);

    conv_x_kernel<<<(N_PAD * 16 + 255) / 256, 256, 0, stream>>>(node_feature, xb);
    conv_w_kernel<<<(126976 + 255) / 256, 256, 0, stream>>>(
        mlp_W, w_ih, w_hh, w1b, wihp, whhb);

    hist_kernel<<<(N_EDGES + 255) / 256, 256, 0, stream>>>(
        edge_index, edge_type, counts);
    scan1_kernel<<<NB1, 256, 0, stream>>>(counts, offsets, partials);
    scan2_kernel<<<1, 512, 0, stream>>>(partials, NB1);
    scan3_kernel<<<(NSEG + 255) / 256, 256, 0, stream>>>(offsets, partials, cursor);
    place_kernel<<<(N_EDGES + 255) / 256, 256, 0, stream>>>(
        edge_index, edge_type, edge_weight, cursor, recs);
    gather_kernel<<<(NSEG * 16 + 255) / 256, 256, 0, stream>>>(
        node_feature, offsets, recs, (unsigned*)updb);

    fused_mlp_gru_kernel<<<(N_NODES + 63) / 64, 256, 0, stream>>>(
        updb, w1b, mlp_b, wihp, whhb, b_ih, b_hh, node_feature, xb, out);
}

// Round 6
// 354.138 us; speedup vs baseline: 4.4657x; 1.3828x over previous
//
#include <hip/hip_runtime.h>
#include <hip/hip_bf16.h>
#include <math.h>

// Problem constants (fixed by the reference)
#define N_NODES   100000
#define N_PAD     100032   // padded row count (multiple of 64) for safe OOB reads
#define N_EDGES   1000000
#define D_IN      64
#define T_ET      4
#define H_DIM     256
#define TD        256      // T_ET * D_IN (mlp fan-in)
#define NSEG      400000   // N_NODES * T_ET

typedef __attribute__((ext_vector_type(8))) short short8;   // 8 bf16 (4 VGPRs)
typedef __attribute__((ext_vector_type(4))) float floatx4;  // MFMA C/D

__device__ __forceinline__ unsigned short f2b(float f) {
    __hip_bfloat16 h = __float2bfloat16(f);
    return *reinterpret_cast<unsigned short*>(&h);
}
__device__ __forceinline__ unsigned pack2(float a, float b) {
    return (unsigned)f2b(a) | ((unsigned)f2b(b) << 16);
}

// ---------------------------------------------------------------------------
// CSR build (unchanged): histogram -> scan -> place
// ---------------------------------------------------------------------------
__global__ __launch_bounds__(256) void hist_kernel(
    const int* __restrict__ edge_index, const int* __restrict__ edge_type,
    int* __restrict__ counts)
{
    int e = blockIdx.x * 256 + threadIdx.x;
    if (e >= N_EDGES) return;
    int dst = edge_index[N_EDGES + e];
    int ty  = edge_type[e];
    atomicAdd(&counts[dst * T_ET + ty], 1);
}

__global__ __launch_bounds__(256) void scan1_kernel(
    const int* __restrict__ counts, int* __restrict__ offsets,
    int* __restrict__ partials)
{
    __shared__ int tsum[256];
    const int tid = threadIdx.x;
    const int base = blockIdx.x * 1024 + tid * 4;
    int v[4]; int s = 0;
    #pragma unroll
    for (int i = 0; i < 4; ++i) {
        v[i] = (base + i < NSEG) ? counts[base + i] : 0;
        s += v[i];
    }
    tsum[tid] = s;
    __syncthreads();
    #pragma unroll
    for (int off = 1; off < 256; off <<= 1) {
        int t = (tid >= off) ? tsum[tid - off] : 0;
        __syncthreads();
        tsum[tid] += t;
        __syncthreads();
    }
    int run = tsum[tid] - s;
    #pragma unroll
    for (int i = 0; i < 4; ++i) {
        if (base + i < NSEG) offsets[base + i] = run;
        run += v[i];
    }
    if (tid == 255) partials[blockIdx.x] = tsum[255];
}

__global__ __launch_bounds__(512) void scan2_kernel(int* __restrict__ partials, int nb)
{
    __shared__ int sh[512];
    const int tid = threadIdx.x;
    int v = (tid < nb) ? partials[tid] : 0;
    sh[tid] = v;
    __syncthreads();
    #pragma unroll
    for (int off = 1; off < 512; off <<= 1) {
        int t = (tid >= off) ? sh[tid - off] : 0;
        __syncthreads();
        sh[tid] += t;
        __syncthreads();
    }
    if (tid < nb) partials[tid] = sh[tid] - v;
}

__global__ __launch_bounds__(256) void scan3_kernel(
    int* __restrict__ offsets, const int* __restrict__ partials,
    int* __restrict__ cursor)
{
    int i = blockIdx.x * 256 + threadIdx.x;
    if (i < NSEG) {
        int o = offsets[i] + partials[i >> 10];
        offsets[i] = o;
        cursor[i]  = o;
    }
    if (i == 0) offsets[NSEG] = N_EDGES;
}

__global__ __launch_bounds__(256) void place_kernel(
    const int* __restrict__ edge_index, const int* __restrict__ edge_type,
    const float* __restrict__ edge_w, int* __restrict__ cursor,
    int2* __restrict__ recs)
{
    int e = blockIdx.x * 256 + threadIdx.x;
    if (e >= N_EDGES) return;
    int src = edge_index[e];
    int dst = edge_index[N_EDGES + e];
    int ty  = edge_type[e];
    int seg = dst * T_ET + ty;
    int pos = atomicAdd(&cursor[seg], 1);
    recs[pos] = make_int2(src, __float_as_int(edge_w[e]));
}

// gather: 16 threads per segment -> bf16 update
__global__ __launch_bounds__(256) void gather_kernel(
    const float* __restrict__ x, const int* __restrict__ offsets,
    const int2* __restrict__ recs, unsigned* __restrict__ updb_u32)
{
    int gid = blockIdx.x * 256 + threadIdx.x;
    int seg = gid >> 4;
    int t   = gid & 15;
    if (seg >= NSEG) return;
    int start = offsets[seg];
    int end   = offsets[seg + 1];
    float4 acc = {0.0f, 0.0f, 0.0f, 0.0f};
    for (int p = start; p < end; ++p) {
        int2 r = recs[p];
        float w = __int_as_float(r.y);
        const float4 xv = reinterpret_cast<const float4*>(x)[r.x * 16 + t];
        acc.x += w * xv.x;
        acc.y += w * xv.y;
        acc.z += w * xv.z;
        acc.w += w * xv.w;
    }
    uint2 o;
    o.x = pack2(acc.x, acc.y);
    o.y = pack2(acc.z, acc.w);
    reinterpret_cast<uint2*>(updb_u32)[seg * 16 + t] = o;
}

// ---------------------------------------------------------------------------
// prep: f32 -> bf16 conversions (x padded; w_ih K-permuted to match the
// hidden-LDS pack layout: k(p) = 16*(p>>6) + 64*(p&3) + ((p>>2)&15))
// ---------------------------------------------------------------------------
__global__ __launch_bounds__(256) void conv_x_kernel(
    const float* __restrict__ x, unsigned short* __restrict__ xb)
{
    int i = blockIdx.x * 256 + threadIdx.x;
    if (i >= N_PAD * 16) return;
    int row = i >> 4;
    int srow = row < N_NODES ? row : N_NODES - 1;
    float4 v = reinterpret_cast<const float4*>(x)[srow * 16 + (i & 15)];
    uint2 o;
    o.x = pack2(v.x, v.y);
    o.y = pack2(v.z, v.w);
    reinterpret_cast<uint2*>(xb)[i] = o;
}

__global__ __launch_bounds__(256) void conv_w_kernel(
    const float* __restrict__ w1, const float* __restrict__ wih,
    const float* __restrict__ whh,
    unsigned short* __restrict__ w1b, unsigned short* __restrict__ wihp,
    unsigned short* __restrict__ whhb)
{
    int i = blockIdx.x * 256 + threadIdx.x;
    if (i < 65536) { w1b[i] = f2b(w1[i]); return; }
    i -= 65536;
    if (i < 49152) {
        int n = i >> 8, p = i & 255;
        int k = 16 * (p >> 6) + 64 * (p & 3) + ((p >> 2) & 15);
        wihp[i] = f2b(wih[n * 256 + k]);
        return;
    }
    i -= 49152;
    if (i < 12288) whhb[i] = f2b(whh[i]);
}

// ---------------------------------------------------------------------------
// Fused MLP + GRU, bf16 MFMA, 64 rows/block, 4 waves (wave = 16 rows, all N).
// v2: B-operands staged cooperatively in LDS per K-step (80B row pitch =>
// conflict-free b128 reads), A-fragments preloaded to registers.
// Phase 1: hidden = relu(upd @ W1^T + b1) -> per-wave LDS (K-permuted pack)
// Phase 2: gi = hidden @ wihp^T (K=256), gh = x @ whh^T (K=64), gates local.
// ---------------------------------------------------------------------------
__global__ __launch_bounds__(256) void fused_mlp_gru_kernel(
    const unsigned short* __restrict__ updb,  // [N_PAD][256] bf16
    const unsigned short* __restrict__ w1b,   // [256][256] bf16
    const float* __restrict__ mlp_b,          // [256]
    const unsigned short* __restrict__ wihp,  // [192][256] bf16, K-permuted
    const unsigned short* __restrict__ whhb,  // [192][64]  bf16
    const float* __restrict__ b_ih,           // [192]
    const float* __restrict__ b_hh,           // [192]
    const float* __restrict__ x,              // [N][64] f32
    const unsigned short* __restrict__ xb,    // [N_PAD][64] bf16
    float* __restrict__ out)                  // [N][64] f32
{
    __shared__ uint4 BsV[1280];               // 20480 B: [256 rows][80 B pitch]
    __shared__ uint4 hidV[4][512];            // 4 x 8192 B per-wave hidden

    unsigned char* Bs = reinterpret_cast<unsigned char*>(BsV);

    const int tid = threadIdx.x;
    const int w  = tid >> 6;
    const int l  = tid & 63;
    const int lr = l & 15;     // fragment M/N index
    const int lg = l >> 4;     // k-group (0..3)
    const int rowBase = blockIdx.x * 64 + w * 16;

    // ---- preload phase-1 A fragments (8 K-steps) ----
    short8 af1[8];
    const unsigned short* aRow = updb + (size_t)(rowBase + lr) * 256 + lg * 8;
    #pragma unroll
    for (int kt = 0; kt < 8; ++kt)
        af1[kt] = *reinterpret_cast<const short8*>(aRow + kt * 32);

    floatx4 acc1[16];
    #pragma unroll
    for (int i = 0; i < 16; ++i) acc1[i] = (floatx4){0.f, 0.f, 0.f, 0.f};

    // ---- phase 1: K=256 in 8 staged steps ----
    #pragma unroll
    for (int kt = 0; kt < 8; ++kt) {
        __syncthreads();
        {   // stage w1b[:, kt*32..+32]: thread tid owns row tid (64 B)
            const uint4* src = reinterpret_cast<const uint4*>(
                w1b + (size_t)tid * 256 + kt * 32);
            uint4 v0 = src[0], v1 = src[1], v2 = src[2], v3 = src[3];
            unsigned char* d = Bs + tid * 80;
            *reinterpret_cast<uint4*>(d)      = v0;
            *reinterpret_cast<uint4*>(d + 16) = v1;
            *reinterpret_cast<uint4*>(d + 32) = v2;
            *reinterpret_cast<uint4*>(d + 48) = v3;
        }
        __syncthreads();
        #pragma unroll
        for (int nf = 0; nf < 16; ++nf) {
            short8 bf = *reinterpret_cast<const short8*>(
                Bs + (nf * 16 + lr) * 80 + lg * 16);
            acc1[nf] = __builtin_amdgcn_mfma_f32_16x16x32_bf16(af1[kt], bf, acc1[nf], 0, 0, 0);
        }
    }

    // bias per col (col = nf*16 + lr)
    float b1v[16];
    #pragma unroll
    for (int nf = 0; nf < 16; ++nf) b1v[nf] = mlp_b[nf * 16 + lr];

    // relu + pack to per-wave LDS (K-permuted: p = 64*jj + 4*lr + s,
    // k(p) = 16*jj + 64*s + lr — matched by wihp prep). XOR bank swizzle.
    char* hw = reinterpret_cast<char*>(&hidV[w][0]);
    #pragma unroll
    for (int jj = 0; jj < 4; ++jj) {
        #pragma unroll
        for (int q = 0; q < 4; ++q) {
            int row = lg * 4 + q;
            float v0 = fmaxf(acc1[jj     ][q] + b1v[jj     ], 0.f);
            float v1 = fmaxf(acc1[jj +  4][q] + b1v[jj +  4], 0.f);
            float v2 = fmaxf(acc1[jj +  8][q] + b1v[jj +  8], 0.f);
            float v3 = fmaxf(acc1[jj + 12][q] + b1v[jj + 12], 0.f);
            uint2 pk;
            pk.x = pack2(v0, v1);
            pk.y = pack2(v2, v3);
            int byte = (row * 512 + 128 * jj + 8 * lr) ^ ((row & 7) << 4);
            *reinterpret_cast<uint2*>(hw + byte) = pk;
        }
    }

    // ---- preload phase-2 gh A fragments ----
    short8 af2[2];
    const unsigned short* xRow = xb + (size_t)(rowBase + lr) * 64 + lg * 8;
    #pragma unroll
    for (int kt = 0; kt < 2; ++kt)
        af2[kt] = *reinterpret_cast<const short8*>(xRow + kt * 32);

    floatx4 ai[12], ah[12];
    #pragma unroll
    for (int i = 0; i < 12; ++i) {
        ai[i] = (floatx4){0.f, 0.f, 0.f, 0.f};
        ah[i] = (floatx4){0.f, 0.f, 0.f, 0.f};
    }

    // ---- phase 2: gi (8 steps from wihp) + gh (2 steps from whhb) ----
    #pragma unroll
    for (int kt = 0; kt < 10; ++kt) {
        __syncthreads();
        if (kt < 8) {
            if (tid < 192) {
                const uint4* src = reinterpret_cast<const uint4*>(
                    wihp + (size_t)tid * 256 + kt * 32);
                uint4 v0 = src[0], v1 = src[1], v2 = src[2], v3 = src[3];
                unsigned char* d = Bs + tid * 80;
                *reinterpret_cast<uint4*>(d)      = v0;
                *reinterpret_cast<uint4*>(d + 16) = v1;
                *reinterpret_cast<uint4*>(d + 32) = v2;
                *reinterpret_cast<uint4*>(d + 48) = v3;
            }
        } else {
            if (tid < 192) {
                const uint4* src = reinterpret_cast<const uint4*>(
                    whhb + (size_t)tid * 64 + (kt - 8) * 32);
                uint4 v0 = src[0], v1 = src[1], v2 = src[2], v3 = src[3];
                unsigned char* d = Bs + tid * 80;
                *reinterpret_cast<uint4*>(d)      = v0;
                *reinterpret_cast<uint4*>(d + 16) = v1;
                *reinterpret_cast<uint4*>(d + 32) = v2;
                *reinterpret_cast<uint4*>(d + 48) = v3;
            }
        }
        __syncthreads();
        if (kt < 8) {
            int byte = (lr * 512 + kt * 64 + lg * 16) ^ ((lr & 7) << 4);
            short8 af = *reinterpret_cast<const short8*>(hw + byte);
            #pragma unroll
            for (int nf = 0; nf < 12; ++nf) {
                short8 bf = *reinterpret_cast<const short8*>(
                    Bs + (nf * 16 + lr) * 80 + lg * 16);
                ai[nf] = __builtin_amdgcn_mfma_f32_16x16x32_bf16(af, bf, ai[nf], 0, 0, 0);
            }
        } else {
            short8 af = af2[kt - 8];
            #pragma unroll
            for (int nf = 0; nf < 12; ++nf) {
                short8 bf = *reinterpret_cast<const short8*>(
                    Bs + (nf * 16 + lr) * 80 + lg * 16);
                ah[nf] = __builtin_amdgcn_mfma_f32_16x16x32_bf16(af, bf, ah[nf], 0, 0, 0);
            }
        }
    }

    // ---- gates + output (thread-local; fast exp) ----
    #pragma unroll
    for (int nf = 0; nf < 4; ++nf) {
        int c = nf * 16 + lr;
        float bir = b_ih[c], biz = b_ih[64 + c], bin = b_ih[128 + c];
        float bhr = b_hh[c], bhz = b_hh[64 + c], bhn = b_hh[128 + c];
        #pragma unroll
        for (int q = 0; q < 4; ++q) {
            int row = rowBase + lg * 4 + q;
            if (row < N_NODES) {
                float ir = ai[nf    ][q] + bir;
                float iz = ai[nf + 4][q] + biz;
                float in_= ai[nf + 8][q] + bin;
                float hr = ah[nf    ][q] + bhr;
                float hz = ah[nf + 4][q] + bhz;
                float hn = ah[nf + 8][q] + bhn;
                float r = 1.0f / (1.0f + __expf(-(ir + hr)));
                float z = 1.0f / (1.0f + __expf(-(iz + hz)));
                float a = in_ + r * hn;
                a = fminf(fmaxf(a, -30.f), 30.f);
                float e2 = __expf(2.0f * a);
                float n = (e2 - 1.0f) / (e2 + 1.0f);
                float xv = x[(size_t)row * 64 + c];
                out[(size_t)row * 64 + c] = (1.0f - z) * n + z * xv;
            }
        }
    }
}

// ---------------------------------------------------------------------------
extern "C" void kernel_launch(void* const* d_in, const int* in_sizes, int n_in,
                              void* d_out, int out_size, void* d_ws, size_t ws_size,
                              hipStream_t stream) {
    const float* node_feature = (const float*)d_in[0];
    const int*   edge_index   = (const int*)d_in[1];
    const int*   edge_type    = (const int*)d_in[2];
    const float* edge_weight  = (const float*)d_in[3];
    const float* mlp_W        = (const float*)d_in[4];
    const float* mlp_b        = (const float*)d_in[5];
    const float* w_ih         = (const float*)d_in[6];
    const float* w_hh         = (const float*)d_in[7];
    const float* b_ih         = (const float*)d_in[8];
    const float* b_hh         = (const float*)d_in[9];
    float* out = (float*)d_out;

    // workspace layout (bf16 regions first, then CSR ints)
    unsigned short* updb = (unsigned short*)d_ws;          // [N_PAD][256]
    unsigned short* xb   = updb + (size_t)N_PAD * 256;     // [N_PAD][64]
    unsigned short* w1b  = xb   + (size_t)N_PAD * 64;      // [256][256]
    unsigned short* wihp = w1b  + 65536;                   // [192][256]
    unsigned short* whhb = wihp + 49152;                   // [192][64]
    int* counts   = (int*)(whhb + 12288);                  // [NSEG]
    int* offsets  = counts + 400064;                       // [NSEG+1]
    int* partials = offsets + 400064;                      // [512]
    int* cursor   = partials + 512;                        // [NSEG]
    int2* recs    = (int2*)(cursor + 400064);              // [E]

    const int NB1 = (NSEG + 1023) / 1024;

    hipMemsetAsync(counts, 0, (size_t)NSEG * sizeof(int), stream);

    conv_x_kernel<<<(N_PAD * 16 + 255) / 256, 256, 0, stream>>>(node_feature, xb);
    conv_w_kernel<<<(126976 + 255) / 256, 256, 0, stream>>>(
        mlp_W, w_ih, w_hh, w1b, wihp, whhb);

    hist_kernel<<<(N_EDGES + 255) / 256, 256, 0, stream>>>(
        edge_index, edge_type, counts);
    scan1_kernel<<<NB1, 256, 0, stream>>>(counts, offsets, partials);
    scan2_kernel<<<1, 512, 0, stream>>>(partials, NB1);
    scan3_kernel<<<(NSEG + 255) / 256, 256, 0, stream>>>(offsets, partials, cursor);
    place_kernel<<<(N_EDGES + 255) / 256, 256, 0, stream>>>(
        edge_index, edge_type, edge_weight, cursor, recs);
    gather_kernel<<<(NSEG * 16 + 255) / 256, 256, 0, stream>>>(
        node_feature, offsets, recs, (unsigned*)updb);

    fused_mlp_gru_kernel<<<(N_NODES + 63) / 64, 256, 0, stream>>>(
        updb, w1b, mlp_b, wihp, whhb, b_ih, b_hh, node_feature, xb, out);
}